// Round 6
// baseline (278.343 us; speedup 1.0000x reference)
//
#include <hip/hip_runtime.h>
#include <hip/hip_bf16.h>

typedef unsigned short u16;
typedef __attribute__((ext_vector_type(8))) short bf16x8;
typedef __attribute__((ext_vector_type(4))) float f32x4;

#define MFMA16(a, b, c) __builtin_amdgcn_mfma_f32_16x16x32_bf16((a), (b), (c), 0, 0, 0)

__device__ __forceinline__ u16 f2bf(float f) {
  union { float f; unsigned u; } v; v.f = f;
  unsigned r = v.u + 0x7fffu + ((v.u >> 16) & 1u);  // RNE
  return (u16)(r >> 16);
}

// pack two fp32 -> dword of 2 bf16 by truncation (1 VALU op)
__device__ __forceinline__ unsigned pk_trunc(float hi, float lo) {
  union { float f; unsigned u; } a, b; a.f = hi; b.f = lo;
  return __builtin_amdgcn_perm(a.u, b.u, 0x07060302u);
}

__device__ __forceinline__ void gload_lds16(const u16* g, u16* l) {
  __builtin_amdgcn_global_load_lds((const __attribute__((address_space(1))) void*)g,
                                   (__attribute__((address_space(3))) void*)l, 16, 0, 0);
}

// ---------------- fp32 -> bf16 convert: 8 elems/thread ----------------
__global__ __launch_bounds__(256) void convert_bf16_k(const float* __restrict__ in,
                                                      u16* __restrict__ out, int n) {
  int i = (blockIdx.x * 256 + threadIdx.x) * 8;
  if (i >= n) return;
  float4 v0 = *(const float4*)(in + i);
  float4 v1 = *(const float4*)(in + i + 4);
  uint4 o;
  o.x = (unsigned)f2bf(v0.x) | ((unsigned)f2bf(v0.y) << 16);
  o.y = (unsigned)f2bf(v0.z) | ((unsigned)f2bf(v0.w) << 16);
  o.z = (unsigned)f2bf(v1.x) | ((unsigned)f2bf(v1.y) << 16);
  o.w = (unsigned)f2bf(v1.z) | ((unsigned)f2bf(v1.w) << 16);
  *(uint4*)(out + i) = o;
}

// ---------------- fused transposes: Wa [1024][3072] and Wp [1024][1024] -> bf16 [N][K] ----------------
__global__ __launch_bounds__(256) void transpose2_k(const float* __restrict__ Wa, u16* __restrict__ WaT,
                                                    const float* __restrict__ Wp, u16* __restrict__ WpT) {
  __shared__ float tile[64][65];
  int b = blockIdx.x;
  const float* W; u16* Wt; int N, n0, k0;
  if (b < 768) { W = Wa; Wt = WaT; N = 3072; n0 = (b % 48) * 64; k0 = (b / 48) * 64; }
  else { int c = b - 768; W = Wp; Wt = WpT; N = 1024; n0 = (c & 15) * 64; k0 = (c >> 4) * 64; }
  const int tx = threadIdx.x & 63, ty = threadIdx.x >> 6;
#pragma unroll
  for (int i = 0; i < 16; ++i)
    tile[ty + 4 * i][tx] = W[(size_t)(k0 + ty + 4 * i) * N + n0 + tx];
  __syncthreads();
#pragma unroll
  for (int i = 0; i < 16; ++i)
    Wt[(size_t)(n0 + ty + 4 * i) * 1024 + k0 + tx] = f2bf(tile[tx][ty + 4 * i]);
}

// ---------------- ring-4 GEMM core: BK=32, 512 thr (8 waves 2M x 4N) ----------------
#define BAR() asm volatile("s_barrier" ::: "memory")
#define WLG()                                                   \
  do {                                                          \
    asm volatile("s_waitcnt lgkmcnt(0)" ::: "memory");          \
    __builtin_amdgcn_sched_barrier(0);                          \
  } while (0)
#define VMW(N) asm volatile("s_waitcnt vmcnt(" #N ")" ::: "memory")

#define RING_LANE_CONSTS                                                    \
  const int tid = threadIdx.x, w = tid >> 6, lane = tid & 63;               \
  const int wm = w >> 2, wn = w & 3;                                        \
  const int fr = lane & 15, fg = lane >> 4;                                 \
  const int sr = lane >> 2;                                                 \
  const int sk = (lane & 1) * 8 + ((((lane >> 1) ^ (lane >> 5)) & 1) << 4); \
  const int lsw = fr * 32 + ((fg * 8) ^ ((fr & 8) ? 16 : 0));

// ---------------- QKV GEMM: 256x256 tile, ring-4, K=1024 (32 K-tiles of 32) ----------------
__global__ __launch_bounds__(512, 2) void gemm_qkv_r4(const u16* __restrict__ A,
                                                      const u16* __restrict__ Bt,
                                                      const float* __restrict__ bias,
                                                      u16* __restrict__ Qo, u16* __restrict__ Ko,
                                                      u16* __restrict__ Vt) {
  __shared__ u16 sm[4][16384];
  const int bid = blockIdx.x;
  const int swz = (bid & 7) * 48 + (bid >> 3);  // 384 % 8 == 0 -> bijective
  const int m0 = (swz / 12) * 256, n0 = (swz % 12) * 256;
  RING_LANE_CONSTS
  const int aoff = wm * 4096 + lsw;
  const int boff = 8192 + wn * 2048 + lsw;

  const u16* gAw = A + (size_t)(m0 + sr) * 1024 + sk + (size_t)w * 16384;
  const u16* gBw = Bt + (size_t)(n0 + sr) * 1024 + sk + (size_t)w * 16384;

#define QSTG_A(SL, C, KO) \
  gload_lds16(gAw + (size_t)(C) * 131072 + (KO), &sm[SL][(C) * 4096 + w * 512 + lane * 8])
#define QSTG_B(SL, C, KO) \
  gload_lds16(gBw + (size_t)(C) * 131072 + (KO), &sm[SL][8192 + (C) * 4096 + w * 512 + lane * 8])

  f32x4 acc[8][4];
#pragma unroll
  for (int i = 0; i < 8; ++i)
#pragma unroll
    for (int j = 0; j < 4; ++j) acc[i][j] = (f32x4){0, 0, 0, 0};

  QSTG_A(0, 0, 0);  QSTG_B(0, 0, 0);  QSTG_A(0, 1, 0);  QSTG_B(0, 1, 0);
  QSTG_A(1, 0, 32); QSTG_B(1, 0, 32); QSTG_A(1, 1, 32); QSTG_B(1, 1, 32);
  QSTG_A(2, 0, 64); QSTG_B(2, 0, 64); QSTG_A(2, 1, 64); QSTG_B(2, 1, 64);
  int kofs = 96;
  VMW(8); BAR();

#define QLD_A(SL, M0_)                                                    \
  _Pragma("unroll") for (int i = 0; i < 4; ++i)                           \
      av[i] = *(const bf16x8*)&sm[SL][aoff + ((M0_) + i) * 512];
#define QLD_B(SL)                                                         \
  _Pragma("unroll") for (int i = 0; i < 4; ++i)                           \
      bv[i] = *(const bf16x8*)&sm[SL][boff + i * 512];
#define QMM(MB0)                                                          \
  __builtin_amdgcn_s_setprio(1);                                          \
  _Pragma("unroll") for (int i = 0; i < 4; ++i)                           \
      _Pragma("unroll") for (int j = 0; j < 4; ++j)                       \
          acc[(MB0) + i][j] = MFMA16(av[i], bv[j], acc[(MB0) + i][j]);    \
  __builtin_amdgcn_s_setprio(0);

#define QTILE(SL, SS, STG, CHK)                                                \
  {                                                                            \
    bf16x8 av[4], bv[4];                                                       \
    QLD_A(SL, 0) QLD_B(SL)                                                     \
    if (STG) { QSTG_A(SS, 0, kofs); QSTG_B(SS, 0, kofs); }                     \
    BAR(); WLG(); QMM(0) BAR();                                                \
    QLD_A(SL, 4)                                                               \
    if (STG) { QSTG_A(SS, 1, kofs); QSTG_B(SS, 1, kofs); }                     \
    BAR(); WLG(); QMM(4)                                                       \
    CHK;                                                                       \
    BAR();                                                                     \
    kofs += 32;                                                                \
  }

#pragma unroll 1
  for (int tp = 0; tp < 7; ++tp) {
    QTILE(0, 3, 1, VMW(8)) QTILE(1, 0, 1, VMW(8)) QTILE(2, 1, 1, VMW(8)) QTILE(3, 2, 1, VMW(8))
  }
  QTILE(0, 3, 1, VMW(8))   // t=28 (stages tile 31)
  QTILE(1, 0, 0, VMW(4))   // t=29
  QTILE(2, 0, 0, VMW(0))   // t=30
  QTILE(3, 0, 0, (void)0)  // t=31

  const int which = n0 >> 10;  // block-uniform: 0=Q, 1=K, 2=V
#pragma unroll
  for (int nb = 0; nb < 4; ++nb) {
    const int n = n0 + wn * 64 + nb * 16 + fr;
    const float bs = bias[n];
    const int c = n & 1023, h = c >> 6, hd = c & 63;
#pragma unroll
    for (int mb = 0; mb < 8; ++mb) {
      const int mbase = m0 + wm * 128 + mb * 16 + fg * 4;
      const int bb = mbase >> 11;
      const int tt = mbase & 2047;
      if (which == 0) {
        u16* dst = Qo + ((size_t)(bb * 16 + h) * 2048 + tt) * 64 + hd;
#pragma unroll
        for (int r = 0; r < 4; ++r) dst[(size_t)r * 64] = f2bf((acc[mb][nb][r] + bs) * 0.125f);
      } else if (which == 1) {
        u16* dst = Ko + ((size_t)(bb * 16 + h) * 2048 + tt) * 64 + hd;
#pragma unroll
        for (int r = 0; r < 4; ++r) dst[(size_t)r * 64] = f2bf(acc[mb][nb][r] + bs);
      } else {
        ushort4 pv;
        pv.x = f2bf(acc[mb][nb][0] + bs);
        pv.y = f2bf(acc[mb][nb][1] + bs);
        pv.z = f2bf(acc[mb][nb][2] + bs);
        pv.w = f2bf(acc[mb][nb][3] + bs);
        *(ushort4*)(Vt + ((size_t)(bb * 16 + h) * 64 + hd) * 2048 + tt) = pv;
      }
    }
  }
#undef QSTG_A
#undef QSTG_B
#undef QLD_A
#undef QLD_B
#undef QMM
#undef QTILE
}

// ---------------- DIAGNOSTIC PROBE: exact ring-4 K-loop, NO epilogue, grid 128 ----------------
// 1 block/CU, zero tail, zero queueing -> measures pure per-block K-loop time.
// acc kept live via full sum + per-thread store (no DCE). Output overlays Yb (dead until attn).
__global__ __launch_bounds__(512, 2) void gemm_qkv_probe(const u16* __restrict__ A,
                                                         const u16* __restrict__ Bt,
                                                         float* __restrict__ P) {
  __shared__ u16 sm[4][16384];
  const int bid = blockIdx.x;
  const int m0 = (bid / 12) * 256, n0 = (bid % 12) * 256;
  RING_LANE_CONSTS
  const int aoff = wm * 4096 + lsw;
  const int boff = 8192 + wn * 2048 + lsw;

  const u16* gAw = A + (size_t)(m0 + sr) * 1024 + sk + (size_t)w * 16384;
  const u16* gBw = Bt + (size_t)(n0 + sr) * 1024 + sk + (size_t)w * 16384;

#define ZSTG_A(SL, C, KO) \
  gload_lds16(gAw + (size_t)(C) * 131072 + (KO), &sm[SL][(C) * 4096 + w * 512 + lane * 8])
#define ZSTG_B(SL, C, KO) \
  gload_lds16(gBw + (size_t)(C) * 131072 + (KO), &sm[SL][8192 + (C) * 4096 + w * 512 + lane * 8])

  f32x4 acc[8][4];
#pragma unroll
  for (int i = 0; i < 8; ++i)
#pragma unroll
    for (int j = 0; j < 4; ++j) acc[i][j] = (f32x4){0, 0, 0, 0};

  ZSTG_A(0, 0, 0);  ZSTG_B(0, 0, 0);  ZSTG_A(0, 1, 0);  ZSTG_B(0, 1, 0);
  ZSTG_A(1, 0, 32); ZSTG_B(1, 0, 32); ZSTG_A(1, 1, 32); ZSTG_B(1, 1, 32);
  ZSTG_A(2, 0, 64); ZSTG_B(2, 0, 64); ZSTG_A(2, 1, 64); ZSTG_B(2, 1, 64);
  int kofs = 96;
  VMW(8); BAR();

#define ZLD_A(SL, M0_)                                                    \
  _Pragma("unroll") for (int i = 0; i < 4; ++i)                           \
      av[i] = *(const bf16x8*)&sm[SL][aoff + ((M0_) + i) * 512];
#define ZLD_B(SL)                                                         \
  _Pragma("unroll") for (int i = 0; i < 4; ++i)                           \
      bv[i] = *(const bf16x8*)&sm[SL][boff + i * 512];
#define ZMM(MB0)                                                          \
  __builtin_amdgcn_s_setprio(1);                                          \
  _Pragma("unroll") for (int i = 0; i < 4; ++i)                           \
      _Pragma("unroll") for (int j = 0; j < 4; ++j)                       \
          acc[(MB0) + i][j] = MFMA16(av[i], bv[j], acc[(MB0) + i][j]);    \
  __builtin_amdgcn_s_setprio(0);

#define ZTILE(SL, SS, STG, CHK)                                                \
  {                                                                            \
    bf16x8 av[4], bv[4];                                                       \
    ZLD_A(SL, 0) ZLD_B(SL)                                                     \
    if (STG) { ZSTG_A(SS, 0, kofs); ZSTG_B(SS, 0, kofs); }                     \
    BAR(); WLG(); ZMM(0) BAR();                                                \
    ZLD_A(SL, 4)                                                               \
    if (STG) { ZSTG_A(SS, 1, kofs); ZSTG_B(SS, 1, kofs); }                     \
    BAR(); WLG(); ZMM(4)                                                       \
    CHK;                                                                       \
    BAR();                                                                     \
    kofs += 32;                                                                \
  }

#pragma unroll 1
  for (int tp = 0; tp < 7; ++tp) {
    ZTILE(0, 3, 1, VMW(8)) ZTILE(1, 0, 1, VMW(8)) ZTILE(2, 1, 1, VMW(8)) ZTILE(3, 2, 1, VMW(8))
  }
  ZTILE(0, 3, 1, VMW(8))
  ZTILE(1, 0, 0, VMW(4))
  ZTILE(2, 0, 0, VMW(0))
  ZTILE(3, 0, 0, (void)0)

  // keep-alive epilogue: consume every acc element, one 4B store per thread
  float s = 0.f;
#pragma unroll
  for (int i = 0; i < 8; ++i)
#pragma unroll
    for (int j = 0; j < 4; ++j)
      s += acc[i][j][0] + acc[i][j][1] + acc[i][j][2] + acc[i][j][3];
  P[(size_t)bid * 512 + tid] = s;
#undef ZSTG_A
#undef ZSTG_B
#undef ZLD_A
#undef ZLD_B
#undef ZMM
#undef ZTILE
}

// ---------------- Proj GEMM: 256x128 tile, ring-4; grid = 256 = 1 full round ----------------
__global__ __launch_bounds__(512, 2) void gemm_proj_r4(const u16* __restrict__ A,
                                                       const u16* __restrict__ Bt,
                                                       const float* __restrict__ bias,
                                                       float* __restrict__ O) {
  __shared__ u16 sm[4][12288];
  const int bid = blockIdx.x;
  const int swz = (bid & 7) * 32 + (bid >> 3);  // 256 % 8 == 0 -> bijective
  const int m0 = (swz >> 3) * 256, n0 = (swz & 7) * 128;
  RING_LANE_CONSTS
  const int aoff = wm * 4096 + lsw;
  const int boff = 8192 + wn * 1024 + lsw;

  const u16* gAw = A + (size_t)(m0 + sr) * 1024 + sk + (size_t)w * 16384;
  const u16* gBw = Bt + (size_t)(n0 + sr) * 1024 + sk + (size_t)w * 16384;

#define PSTG_A(SL, C, KO) \
  gload_lds16(gAw + (size_t)(C) * 131072 + (KO), &sm[SL][(C) * 4096 + w * 512 + lane * 8])
#define PSTG_B(SL, KO) \
  gload_lds16(gBw + (KO), &sm[SL][8192 + w * 512 + lane * 8])

  f32x4 acc[8][2];
#pragma unroll
  for (int i = 0; i < 8; ++i)
#pragma unroll
    for (int j = 0; j < 2; ++j) acc[i][j] = (f32x4){0, 0, 0, 0};

  PSTG_A(0, 0, 0);  PSTG_B(0, 0);  PSTG_A(0, 1, 0);
  PSTG_A(1, 0, 32); PSTG_B(1, 32); PSTG_A(1, 1, 32);
  PSTG_A(2, 0, 64); PSTG_B(2, 64); PSTG_A(2, 1, 64);
  int kofs = 96;
  VMW(6); BAR();

#define PLD_A(SL, M0_)                                                    \
  _Pragma("unroll") for (int i = 0; i < 4; ++i)                           \
      av[i] = *(const bf16x8*)&sm[SL][aoff + ((M0_) + i) * 512];
#define PLD_B(SL)                                                         \
  _Pragma("unroll") for (int i = 0; i < 2; ++i)                           \
      bv[i] = *(const bf16x8*)&sm[SL][boff + i * 512];
#define PMM(MB0)                                                          \
  __builtin_amdgcn_s_setprio(1);                                          \
  _Pragma("unroll") for (int i = 0; i < 4; ++i)                           \
      _Pragma("unroll") for (int j = 0; j < 2; ++j)                       \
          acc[(MB0) + i][j] = MFMA16(av[i], bv[j], acc[(MB0) + i][j]);    \
  __builtin_amdgcn_s_setprio(0);

#define PTILE(SL, SS, STG, CHK)                                                \
  {                                                                            \
    bf16x8 av[4], bv[2];                                                       \
    PLD_A(SL, 0) PLD_B(SL)                                                     \
    if (STG) { PSTG_A(SS, 0, kofs); PSTG_B(SS, kofs); }                        \
    BAR(); WLG(); PMM(0) BAR();                                                \
    PLD_A(SL, 4)                                                               \
    if (STG) { PSTG_A(SS, 1, kofs); }                                          \
    BAR(); WLG(); PMM(4)                                                       \
    CHK;                                                                       \
    BAR();                                                                     \
    kofs += 32;                                                                \
  }

#pragma unroll 1
  for (int tp = 0; tp < 7; ++tp) {
    PTILE(0, 3, 1, VMW(6)) PTILE(1, 0, 1, VMW(6)) PTILE(2, 1, 1, VMW(6)) PTILE(3, 2, 1, VMW(6))
  }
  PTILE(0, 3, 1, VMW(6))
  PTILE(1, 0, 0, VMW(3))
  PTILE(2, 0, 0, VMW(0))
  PTILE(3, 0, 0, (void)0)

#pragma unroll
  for (int nb = 0; nb < 2; ++nb) {
    const int n = n0 + wn * 32 + nb * 16 + fr;
    const float bs = bias[n];
#pragma unroll
    for (int mb = 0; mb < 8; ++mb) {
      const int tg = m0 + wm * 128 + mb * 16 + fg * 4;
#pragma unroll
      for (int r = 0; r < 4; ++r) O[(size_t)(tg + r) * 1024 + n] = acc[mb][nb][r] + bs;
    }
  }
#undef PSTG_A
#undef PSTG_B
#undef PLD_A
#undef PLD_B
#undef PMM
#undef PTILE
}

// ---------------- Flash attention: 128 q/block (32/wave), balanced qt map + T5 setprio ----------------
// qt remap g=[15,14,13,12, 0,1,2,3, 11,10,9,8, 4,5,6,7]: each CU's 4 blocks (slot>>3
// indices {i,i+4,i+8,i+12}) sum to exactly 30 jt-units -> uniform per-CU work.
#define PSTR 72
__global__ __launch_bounds__(256) void attn_k(const u16* __restrict__ Q,
                                              const u16* __restrict__ Kb,
                                              const u16* __restrict__ Vt,
                                              u16* __restrict__ Y) {
  __shared__ u16 Ks[64 * 72];
  __shared__ u16 Vs[64 * 72];
  __shared__ u16 Ps[4 * 32 * PSTR];
  const int L = blockIdx.x;
  const int xcd = L & 7, slot = L >> 3;
  const int bh = xcd * 8 + (slot & 7);
  const int i2 = slot >> 3;
  const int qt = (i2 & 4) ? ((i2 & 8) ? 4 + (i2 & 3) : (i2 & 3))
                          : ((i2 & 8) ? 11 - (i2 & 3) : 15 - (i2 & 3));
  const int tid = threadIdx.x, w = tid >> 6, lane = tid & 63;
  const int fr = lane & 15, fg = lane >> 4;
  const u16* Qp = Q + (size_t)bh * 2048 * 64;
  const u16* Kp = Kb + (size_t)bh * 2048 * 64;
  const u16* Vp = Vt + (size_t)bh * 64 * 2048;
  const int qw = qt * 128 + w * 32;

  bf16x8 qa[2][2];
#pragma unroll
  for (int g = 0; g < 2; ++g)
#pragma unroll
    for (int c = 0; c < 2; ++c)
      qa[g][c] = *(const bf16x8*)(Qp + (size_t)(qw + g * 16 + fr) * 64 + c * 32 + fg * 8);

  float li[2] = {0.f, 0.f};
  f32x4 ot[2][4];
#pragma unroll
  for (int g = 0; g < 2; ++g)
#pragma unroll
    for (int mb = 0; mb < 4; ++mb) ot[g][mb] = (f32x4){0, 0, 0, 0};

  const int srow = tid >> 2, scol = (tid & 3) * 16;
  u16* Pw = Ps + w * 32 * PSTR;
  const int nk = 2 * qt + 2;
  const u16* Kg = Kp + (size_t)srow * 64 + scol;
  const u16* Vg = Vp + (size_t)srow * 2048 + scol;

  uint4 kr0 = *(const uint4*)(Kg);
  uint4 kr1 = *(const uint4*)(Kg + 8);
  uint4 vr0 = *(const uint4*)(Vg);
  uint4 vr1 = *(const uint4*)(Vg + 8);

  for (int jt = 0; jt < nk; ++jt) {
    const int k0 = jt * 64;
    if (jt) __syncthreads();
    *(uint4*)&Ks[srow * 72 + scol] = kr0;
    *(uint4*)&Ks[srow * 72 + scol + 8] = kr1;
    *(uint4*)&Vs[srow * 72 + scol] = vr0;
    *(uint4*)&Vs[srow * 72 + scol + 8] = vr1;
    __syncthreads();
    if (jt + 1 < nk) {
      const int kn = (jt + 1) * 64;
      kr0 = *(const uint4*)(Kg + (size_t)kn * 64);
      kr1 = *(const uint4*)(Kg + (size_t)kn * 64 + 8);
      vr0 = *(const uint4*)(Vg + kn);
      vr1 = *(const uint4*)(Vg + kn + 8);
    }
    if (k0 > qw + 31) continue;

    bf16x8 kb[4][2];
#pragma unroll
    for (int nb = 0; nb < 4; ++nb) {
      kb[nb][0] = *(const bf16x8*)&Ks[(nb * 16 + fr) * 72 + fg * 8];
      kb[nb][1] = *(const bf16x8*)&Ks[(nb * 16 + fr) * 72 + 32 + fg * 8];
    }
    f32x4 st[2][4];
    __builtin_amdgcn_s_setprio(1);
#pragma unroll
    for (int g = 0; g < 2; ++g)
#pragma unroll
      for (int nb = 0; nb < 4; ++nb) {
        f32x4 z = (f32x4){0, 0, 0, 0};
        z = MFMA16(kb[nb][0], qa[g][0], z);
        z = MFMA16(kb[nb][1], qa[g][1], z);
        st[g][nb] = z;
      }
    __builtin_amdgcn_s_setprio(0);
    const bool needmask = (k0 + 63 > qw);
#pragma unroll
    for (int g = 0; g < 2; ++g) {
      const int q = qw + g * 16 + fr;
      float rs0 = 0.f, rs1 = 0.f;
#pragma unroll
      for (int nb = 0; nb < 4; ++nb) {
        const int kcb = k0 + nb * 16 + 4 * fg;
        float p0 = __expf(st[g][nb][0]);
        float p1 = __expf(st[g][nb][1]);
        float p2 = __expf(st[g][nb][2]);
        float p3 = __expf(st[g][nb][3]);
        if (needmask) {
          p0 = (kcb + 0 > q) ? 0.f : p0;
          p1 = (kcb + 1 > q) ? 0.f : p1;
          p2 = (kcb + 2 > q) ? 0.f : p2;
          p3 = (kcb + 3 > q) ? 0.f : p3;
        }
        rs0 += p0 + p1;
        rs1 += p2 + p3;
        *(uint2*)&Pw[(g * 16 + fr) * PSTR + nb * 16 + 4 * fg] =
            make_uint2(pk_trunc(p1, p0), pk_trunc(p3, p2));
      }
      li[g] += rs0 + rs1;
    }
    bf16x8 pa[2][2];
#pragma unroll
    for (int g = 0; g < 2; ++g)
#pragma unroll
      for (int H = 0; H < 2; ++H)
        pa[g][H] = *(const bf16x8*)&Pw[(g * 16 + fr) * PSTR + H * 32 + fg * 8];
    __builtin_amdgcn_s_setprio(1);
#pragma unroll
    for (int mb = 0; mb < 4; ++mb) {
      bf16x8 vb0 = *(const bf16x8*)&Vs[(mb * 16 + fr) * 72 + fg * 8];
      bf16x8 vb1 = *(const bf16x8*)&Vs[(mb * 16 + fr) * 72 + 32 + fg * 8];
#pragma unroll
      for (int g = 0; g < 2; ++g) {
        ot[g][mb] = MFMA16(vb0, pa[g][0], ot[g][mb]);
        ot[g][mb] = MFMA16(vb1, pa[g][1], ot[g][mb]);
      }
    }
    __builtin_amdgcn_s_setprio(0);
  }

  const int b = bh >> 4, h = bh & 15;
#pragma unroll
  for (int g = 0; g < 2; ++g) {
    float l = li[g];
    l += __shfl_xor(l, 16);
    l += __shfl_xor(l, 32);
    const float inv = 1.0f / l;
    const int t = qw + g * 16 + fr;
    u16* yrow = Y + ((size_t)b * 2048 + t) * 1024 + h * 64;
#pragma unroll
    for (int mb = 0; mb < 4; ++mb) {
      const unsigned d0 = (unsigned)f2bf(ot[g][mb][0] * inv) |
                          ((unsigned)f2bf(ot[g][mb][1] * inv) << 16);
      const unsigned d1 = (unsigned)f2bf(ot[g][mb][2] * inv) |
                          ((unsigned)f2bf(ot[g][mb][3] * inv) << 16);
      *(uint2*)&yrow[mb * 16 + fg * 4] = make_uint2(d0, d1);
    }
  }
}

extern "C" void kernel_launch(void* const* d_in, const int* in_sizes, int n_in,
                              void* d_out, int out_size, void* d_ws, size_t ws_size,
                              hipStream_t stream) {
  const float* x = (const float*)d_in[0];
  const float* Wa = (const float*)d_in[1];
  const float* ba = (const float*)d_in[2];
  const float* Wp = (const float*)d_in[3];
  const float* bp = (const float*)d_in[4];
  float* out = (float*)d_out;

  char* p = (char*)d_ws;
  u16* xb = (u16*)p;   p += (size_t)8192 * 1024 * 2;
  u16* WaT = (u16*)p;  p += (size_t)3072 * 1024 * 2;
  u16* WpT = (u16*)p;  p += (size_t)1024 * 1024 * 2;
  u16* Qb = (u16*)p;   p += (size_t)64 * 2048 * 64 * 2;
  u16* Kbuf = (u16*)p; p += (size_t)64 * 2048 * 64 * 2;
  u16* Vtb = (u16*)p;  p += (size_t)64 * 64 * 2048 * 2;
  u16* Yb = (u16*)p;   p += (size_t)8192 * 1024 * 2;

  convert_bf16_k<<<4096, 256, 0, stream>>>(x, xb, 8192 * 1024);
  transpose2_k<<<1024, 256, 0, stream>>>(Wa, WaT, Wp, WpT);
  gemm_qkv_probe<<<128, 512, 0, stream>>>(xb, WaT, (float*)Yb);  // diagnostic, output dead
  gemm_qkv_r4<<<384, 512, 0, stream>>>(xb, WaT, ba, Qb, Kbuf, Vtb);
  attn_k<<<1024, 256, 0, stream>>>(Qb, Kbuf, Vtb, Yb);
  gemm_proj_r4<<<256, 512, 0, stream>>>(Yb, WpT, bp, out);
}

// Round 8
// 250.608 us; speedup vs baseline: 1.1107x; 1.1107x over previous
//
#include <hip/hip_runtime.h>
#include <hip/hip_bf16.h>

typedef unsigned short u16;
typedef __attribute__((ext_vector_type(8))) short bf16x8;
typedef __attribute__((ext_vector_type(4))) float f32x4;

#define MFMA16(a, b, c) __builtin_amdgcn_mfma_f32_16x16x32_bf16((a), (b), (c), 0, 0, 0)

__device__ __forceinline__ u16 f2bf(float f) {
  union { float f; unsigned u; } v; v.f = f;
  unsigned r = v.u + 0x7fffu + ((v.u >> 16) & 1u);  // RNE
  return (u16)(r >> 16);
}

// pack two fp32 -> dword of 2 bf16 by truncation (1 VALU op)
__device__ __forceinline__ unsigned pk_trunc(float hi, float lo) {
  union { float f; unsigned u; } a, b; a.f = hi; b.f = lo;
  return __builtin_amdgcn_perm(a.u, b.u, 0x07060302u);
}

__device__ __forceinline__ void gload_lds16(const u16* g, u16* l) {
  __builtin_amdgcn_global_load_lds((const __attribute__((address_space(1))) void*)g,
                                   (__attribute__((address_space(3))) void*)l, 16, 0, 0);
}

// ---------------- fp32 -> bf16 convert: 8 elems/thread ----------------
__global__ __launch_bounds__(256) void convert_bf16_k(const float* __restrict__ in,
                                                      u16* __restrict__ out, int n) {
  int i = (blockIdx.x * 256 + threadIdx.x) * 8;
  if (i >= n) return;
  float4 v0 = *(const float4*)(in + i);
  float4 v1 = *(const float4*)(in + i + 4);
  uint4 o;
  o.x = (unsigned)f2bf(v0.x) | ((unsigned)f2bf(v0.y) << 16);
  o.y = (unsigned)f2bf(v0.z) | ((unsigned)f2bf(v0.w) << 16);
  o.z = (unsigned)f2bf(v1.x) | ((unsigned)f2bf(v1.y) << 16);
  o.w = (unsigned)f2bf(v1.z) | ((unsigned)f2bf(v1.w) << 16);
  *(uint4*)(out + i) = o;
}

// ---------------- fused transposes: Wa [1024][3072] and Wp [1024][1024] -> bf16 [N][K] ----------------
__global__ __launch_bounds__(256) void transpose2_k(const float* __restrict__ Wa, u16* __restrict__ WaT,
                                                    const float* __restrict__ Wp, u16* __restrict__ WpT) {
  __shared__ float tile[64][65];
  int b = blockIdx.x;
  const float* W; u16* Wt; int N, n0, k0;
  if (b < 768) { W = Wa; Wt = WaT; N = 3072; n0 = (b % 48) * 64; k0 = (b / 48) * 64; }
  else { int c = b - 768; W = Wp; Wt = WpT; N = 1024; n0 = (c & 15) * 64; k0 = (c >> 4) * 64; }
  const int tx = threadIdx.x & 63, ty = threadIdx.x >> 6;
#pragma unroll
  for (int i = 0; i < 16; ++i)
    tile[ty + 4 * i][tx] = W[(size_t)(k0 + ty + 4 * i) * N + n0 + tx];
  __syncthreads();
#pragma unroll
  for (int i = 0; i < 16; ++i)
    Wt[(size_t)(n0 + ty + 4 * i) * 1024 + k0 + tx] = f2bf(tile[tx][ty + 4 * i]);
}

// ---------------- ring-4 GEMM core: BK=32, 512 thr (8 waves 2M x 4N), ONE barrier/tile ----------------
// Slot disjointness makes intra-tile barriers redundant: reads hit slot SL, stages write
// SS != SL; WAR on SS retired before the previous tile-end barrier; RAW for t+1 enforced
// per-wave by counted VMW(8) (retires the 4 loads staged at t-2) placed before the barrier.
#define BAR() asm volatile("s_barrier" ::: "memory")
#define WLG()                                                   \
  do {                                                          \
    asm volatile("s_waitcnt lgkmcnt(0)" ::: "memory");          \
    __builtin_amdgcn_sched_barrier(0);                          \
  } while (0)
#define VMW(N) asm volatile("s_waitcnt vmcnt(" #N ")" ::: "memory")

#define RING_LANE_CONSTS                                                    \
  const int tid = threadIdx.x, w = tid >> 6, lane = tid & 63;               \
  const int wm = w >> 2, wn = w & 3;                                        \
  const int fr = lane & 15, fg = lane >> 4;                                 \
  const int sr = lane >> 2;                                                 \
  const int sk = (lane & 1) * 8 + ((((lane >> 1) ^ (lane >> 5)) & 1) << 4); \
  const int lsw = fr * 32 + ((fg * 8) ^ ((fr & 8) ? 16 : 0));

// ---------------- QKV GEMM: 256x256 tile, ring-4, K=1024 (32 K-tiles of 32) ----------------
__global__ __launch_bounds__(512, 2) void gemm_qkv_r4(const u16* __restrict__ A,
                                                      const u16* __restrict__ Bt,
                                                      const float* __restrict__ bias,
                                                      u16* __restrict__ Qo, u16* __restrict__ Ko,
                                                      u16* __restrict__ Vt) {
  __shared__ u16 sm[4][16384];
  const int bid = blockIdx.x;
  const int swz = (bid & 7) * 48 + (bid >> 3);  // 384 % 8 == 0 -> bijective
  const int m0 = (swz / 12) * 256, n0 = (swz % 12) * 256;
  RING_LANE_CONSTS
  const int aoff = wm * 4096 + lsw;
  const int boff = 8192 + wn * 2048 + lsw;

  const u16* gAw = A + (size_t)(m0 + sr) * 1024 + sk + (size_t)w * 16384;
  const u16* gBw = Bt + (size_t)(n0 + sr) * 1024 + sk + (size_t)w * 16384;

#define QSTG_A(SL, C, KO) \
  gload_lds16(gAw + (size_t)(C) * 131072 + (KO), &sm[SL][(C) * 4096 + w * 512 + lane * 8])
#define QSTG_B(SL, C, KO) \
  gload_lds16(gBw + (size_t)(C) * 131072 + (KO), &sm[SL][8192 + (C) * 4096 + w * 512 + lane * 8])

  f32x4 acc[8][4];
#pragma unroll
  for (int i = 0; i < 8; ++i)
#pragma unroll
    for (int j = 0; j < 4; ++j) acc[i][j] = (f32x4){0, 0, 0, 0};

  // prologue: stage tiles 0,1,2 into slots 0,1,2; retire tile 0 (vmcnt(8))
  QSTG_A(0, 0, 0);  QSTG_B(0, 0, 0);  QSTG_A(0, 1, 0);  QSTG_B(0, 1, 0);
  QSTG_A(1, 0, 32); QSTG_B(1, 0, 32); QSTG_A(1, 1, 32); QSTG_B(1, 1, 32);
  QSTG_A(2, 0, 64); QSTG_B(2, 0, 64); QSTG_A(2, 1, 64); QSTG_B(2, 1, 64);
  int kofs = 96;
  VMW(8); BAR();

#define QLD_A(SL, M0_)                                                    \
  _Pragma("unroll") for (int i = 0; i < 4; ++i)                           \
      av[i] = *(const bf16x8*)&sm[SL][aoff + ((M0_) + i) * 512];
#define QLD_B(SL)                                                         \
  _Pragma("unroll") for (int i = 0; i < 4; ++i)                           \
      bv[i] = *(const bf16x8*)&sm[SL][boff + i * 512];
#define QMM(MB0)                                                          \
  __builtin_amdgcn_s_setprio(1);                                          \
  _Pragma("unroll") for (int i = 0; i < 4; ++i)                           \
      _Pragma("unroll") for (int j = 0; j < 4; ++j)                       \
          acc[(MB0) + i][j] = MFMA16(av[i], bv[j], acc[(MB0) + i][j]);    \
  __builtin_amdgcn_s_setprio(0);

// ONE barrier per tile: stage t+3 -> SS, read SL, MFMA, counted checkpoint, barrier.
#define QTILE(SL, SS, STG, CHK)                                                \
  {                                                                            \
    bf16x8 av[4], bv[4];                                                       \
    if (STG) { QSTG_A(SS, 0, kofs); QSTG_B(SS, 0, kofs);                       \
               QSTG_A(SS, 1, kofs); QSTG_B(SS, 1, kofs); }                     \
    QLD_A(SL, 0) QLD_B(SL)                                                     \
    WLG(); QMM(0)                                                              \
    QLD_A(SL, 4)                                                               \
    WLG(); QMM(4)                                                              \
    CHK;                                                                       \
    BAR();                                                                     \
    kofs += 32;                                                                \
  }

#pragma unroll 1
  for (int tp = 0; tp < 7; ++tp) {
    QTILE(0, 3, 1, VMW(8)) QTILE(1, 0, 1, VMW(8)) QTILE(2, 1, 1, VMW(8)) QTILE(3, 2, 1, VMW(8))
  }
  QTILE(0, 3, 1, VMW(8))   // t=28 (stages tile 31)
  QTILE(1, 0, 0, VMW(4))   // t=29
  QTILE(2, 0, 0, VMW(0))   // t=30
  QTILE(3, 0, 0, (void)0)  // t=31

  const int which = n0 >> 10;  // block-uniform: 0=Q, 1=K, 2=V
#pragma unroll
  for (int nb = 0; nb < 4; ++nb) {
    const int n = n0 + wn * 64 + nb * 16 + fr;
    const float bs = bias[n];
    const int c = n & 1023, h = c >> 6, hd = c & 63;
#pragma unroll
    for (int mb = 0; mb < 8; ++mb) {
      const int mbase = m0 + wm * 128 + mb * 16 + fg * 4;
      const int bb = mbase >> 11;
      const int tt = mbase & 2047;
      if (which == 0) {
        u16* dst = Qo + ((size_t)(bb * 16 + h) * 2048 + tt) * 64 + hd;
#pragma unroll
        for (int r = 0; r < 4; ++r) dst[(size_t)r * 64] = f2bf((acc[mb][nb][r] + bs) * 0.125f);
      } else if (which == 1) {
        u16* dst = Ko + ((size_t)(bb * 16 + h) * 2048 + tt) * 64 + hd;
#pragma unroll
        for (int r = 0; r < 4; ++r) dst[(size_t)r * 64] = f2bf(acc[mb][nb][r] + bs);
      } else {
        ushort4 pv;
        pv.x = f2bf(acc[mb][nb][0] + bs);
        pv.y = f2bf(acc[mb][nb][1] + bs);
        pv.z = f2bf(acc[mb][nb][2] + bs);
        pv.w = f2bf(acc[mb][nb][3] + bs);
        *(ushort4*)(Vt + ((size_t)(bb * 16 + h) * 64 + hd) * 2048 + tt) = pv;
      }
    }
  }
#undef QSTG_A
#undef QSTG_B
#undef QLD_A
#undef QLD_B
#undef QMM
#undef QTILE
}

// ---------------- Proj GEMM: 256x128 tile, ring-4, ONE barrier/tile; grid = 256 ----------------
__global__ __launch_bounds__(512, 2) void gemm_proj_r4(const u16* __restrict__ A,
                                                       const u16* __restrict__ Bt,
                                                       const float* __restrict__ bias,
                                                       float* __restrict__ O) {
  __shared__ u16 sm[4][12288];
  const int bid = blockIdx.x;
  const int swz = (bid & 7) * 32 + (bid >> 3);  // 256 % 8 == 0 -> bijective
  const int m0 = (swz >> 3) * 256, n0 = (swz & 7) * 128;
  RING_LANE_CONSTS
  const int aoff = wm * 4096 + lsw;
  const int boff = 8192 + wn * 1024 + lsw;

  const u16* gAw = A + (size_t)(m0 + sr) * 1024 + sk + (size_t)w * 16384;
  const u16* gBw = Bt + (size_t)(n0 + sr) * 1024 + sk + (size_t)w * 16384;

#define PSTG_A(SL, C, KO) \
  gload_lds16(gAw + (size_t)(C) * 131072 + (KO), &sm[SL][(C) * 4096 + w * 512 + lane * 8])
#define PSTG_B(SL, KO) \
  gload_lds16(gBw + (KO), &sm[SL][8192 + w * 512 + lane * 8])

  f32x4 acc[8][2];
#pragma unroll
  for (int i = 0; i < 8; ++i)
#pragma unroll
    for (int j = 0; j < 2; ++j) acc[i][j] = (f32x4){0, 0, 0, 0};

  PSTG_A(0, 0, 0);  PSTG_B(0, 0);  PSTG_A(0, 1, 0);
  PSTG_A(1, 0, 32); PSTG_B(1, 32); PSTG_A(1, 1, 32);
  PSTG_A(2, 0, 64); PSTG_B(2, 64); PSTG_A(2, 1, 64);
  int kofs = 96;
  VMW(6); BAR();

#define PLD_A(SL, M0_)                                                    \
  _Pragma("unroll") for (int i = 0; i < 4; ++i)                           \
      av[i] = *(const bf16x8*)&sm[SL][aoff + ((M0_) + i) * 512];
#define PLD_B(SL)                                                         \
  _Pragma("unroll") for (int i = 0; i < 2; ++i)                           \
      bv[i] = *(const bf16x8*)&sm[SL][boff + i * 512];
#define PMM(MB0)                                                          \
  __builtin_amdgcn_s_setprio(1);                                          \
  _Pragma("unroll") for (int i = 0; i < 4; ++i)                           \
      _Pragma("unroll") for (int j = 0; j < 2; ++j)                       \
          acc[(MB0) + i][j] = MFMA16(av[i], bv[j], acc[(MB0) + i][j]);    \
  __builtin_amdgcn_s_setprio(0);

#define PTILE(SL, SS, STG, CHK)                                                \
  {                                                                            \
    bf16x8 av[4], bv[2];                                                       \
    if (STG) { PSTG_A(SS, 0, kofs); PSTG_B(SS, kofs); PSTG_A(SS, 1, kofs); }   \
    PLD_A(SL, 0) PLD_B(SL)                                                     \
    WLG(); PMM(0)                                                              \
    PLD_A(SL, 4)                                                               \
    WLG(); PMM(4)                                                              \
    CHK;                                                                       \
    BAR();                                                                     \
    kofs += 32;                                                                \
  }

#pragma unroll 1
  for (int tp = 0; tp < 7; ++tp) {
    PTILE(0, 3, 1, VMW(6)) PTILE(1, 0, 1, VMW(6)) PTILE(2, 1, 1, VMW(6)) PTILE(3, 2, 1, VMW(6))
  }
  PTILE(0, 3, 1, VMW(6))
  PTILE(1, 0, 0, VMW(3))
  PTILE(2, 0, 0, VMW(0))
  PTILE(3, 0, 0, (void)0)

#pragma unroll
  for (int nb = 0; nb < 2; ++nb) {
    const int n = n0 + wn * 32 + nb * 16 + fr;
    const float bs = bias[n];
#pragma unroll
    for (int mb = 0; mb < 8; ++mb) {
      const int tg = m0 + wm * 128 + mb * 16 + fg * 4;
#pragma unroll
      for (int r = 0; r < 4; ++r) O[(size_t)(tg + r) * 1024 + n] = acc[mb][nb][r] + bs;
    }
  }
#undef PSTG_A
#undef PSTG_B
#undef PLD_A
#undef PLD_B
#undef PMM
#undef PTILE
}

// ---------------- Flash attention: 128 q/block (32/wave), balanced qt map + T5 setprio ----------------
#define PSTR 72
__global__ __launch_bounds__(256) void attn_k(const u16* __restrict__ Q,
                                              const u16* __restrict__ Kb,
                                              const u16* __restrict__ Vt,
                                              u16* __restrict__ Y) {
  __shared__ u16 Ks[64 * 72];
  __shared__ u16 Vs[64 * 72];
  __shared__ u16 Ps[4 * 32 * PSTR];
  const int L = blockIdx.x;
  const int xcd = L & 7, slot = L >> 3;
  const int bh = xcd * 8 + (slot & 7);
  const int i2 = slot >> 3;
  const int qt = (i2 & 4) ? ((i2 & 8) ? 4 + (i2 & 3) : (i2 & 3))
                          : ((i2 & 8) ? 11 - (i2 & 3) : 15 - (i2 & 3));
  const int tid = threadIdx.x, w = tid >> 6, lane = tid & 63;
  const int fr = lane & 15, fg = lane >> 4;
  const u16* Qp = Q + (size_t)bh * 2048 * 64;
  const u16* Kp = Kb + (size_t)bh * 2048 * 64;
  const u16* Vp = Vt + (size_t)bh * 64 * 2048;
  const int qw = qt * 128 + w * 32;

  bf16x8 qa[2][2];
#pragma unroll
  for (int g = 0; g < 2; ++g)
#pragma unroll
    for (int c = 0; c < 2; ++c)
      qa[g][c] = *(const bf16x8*)(Qp + (size_t)(qw + g * 16 + fr) * 64 + c * 32 + fg * 8);

  float li[2] = {0.f, 0.f};
  f32x4 ot[2][4];
#pragma unroll
  for (int g = 0; g < 2; ++g)
#pragma unroll
    for (int mb = 0; mb < 4; ++mb) ot[g][mb] = (f32x4){0, 0, 0, 0};

  const int srow = tid >> 2, scol = (tid & 3) * 16;
  u16* Pw = Ps + w * 32 * PSTR;
  const int nk = 2 * qt + 2;
  const u16* Kg = Kp + (size_t)srow * 64 + scol;
  const u16* Vg = Vp + (size_t)srow * 2048 + scol;

  uint4 kr0 = *(const uint4*)(Kg);
  uint4 kr1 = *(const uint4*)(Kg + 8);
  uint4 vr0 = *(const uint4*)(Vg);
  uint4 vr1 = *(const uint4*)(Vg + 8);

  for (int jt = 0; jt < nk; ++jt) {
    const int k0 = jt * 64;
    if (jt) __syncthreads();
    *(uint4*)&Ks[srow * 72 + scol] = kr0;
    *(uint4*)&Ks[srow * 72 + scol + 8] = kr1;
    *(uint4*)&Vs[srow * 72 + scol] = vr0;
    *(uint4*)&Vs[srow * 72 + scol + 8] = vr1;
    __syncthreads();
    if (jt + 1 < nk) {
      const int kn = (jt + 1) * 64;
      kr0 = *(const uint4*)(Kg + (size_t)kn * 64);
      kr1 = *(const uint4*)(Kg + (size_t)kn * 64 + 8);
      vr0 = *(const uint4*)(Vg + kn);
      vr1 = *(const uint4*)(Vg + kn + 8);
    }
    if (k0 > qw + 31) continue;

    bf16x8 kb[4][2];
#pragma unroll
    for (int nb = 0; nb < 4; ++nb) {
      kb[nb][0] = *(const bf16x8*)&Ks[(nb * 16 + fr) * 72 + fg * 8];
      kb[nb][1] = *(const bf16x8*)&Ks[(nb * 16 + fr) * 72 + 32 + fg * 8];
    }
    f32x4 st[2][4];
    __builtin_amdgcn_s_setprio(1);
#pragma unroll
    for (int g = 0; g < 2; ++g)
#pragma unroll
      for (int nb = 0; nb < 4; ++nb) {
        f32x4 z = (f32x4){0, 0, 0, 0};
        z = MFMA16(kb[nb][0], qa[g][0], z);
        z = MFMA16(kb[nb][1], qa[g][1], z);
        st[g][nb] = z;
      }
    __builtin_amdgcn_s_setprio(0);
    const bool needmask = (k0 + 63 > qw);
#pragma unroll
    for (int g = 0; g < 2; ++g) {
      const int q = qw + g * 16 + fr;
      float rs0 = 0.f, rs1 = 0.f;
#pragma unroll
      for (int nb = 0; nb < 4; ++nb) {
        const int kcb = k0 + nb * 16 + 4 * fg;
        float p0 = __expf(st[g][nb][0]);
        float p1 = __expf(st[g][nb][1]);
        float p2 = __expf(st[g][nb][2]);
        float p3 = __expf(st[g][nb][3]);
        if (needmask) {
          p0 = (kcb + 0 > q) ? 0.f : p0;
          p1 = (kcb + 1 > q) ? 0.f : p1;
          p2 = (kcb + 2 > q) ? 0.f : p2;
          p3 = (kcb + 3 > q) ? 0.f : p3;
        }
        rs0 += p0 + p1;
        rs1 += p2 + p3;
        *(uint2*)&Pw[(g * 16 + fr) * PSTR + nb * 16 + 4 * fg] =
            make_uint2(pk_trunc(p1, p0), pk_trunc(p3, p2));
      }
      li[g] += rs0 + rs1;
    }
    bf16x8 pa[2][2];
#pragma unroll
    for (int g = 0; g < 2; ++g)
#pragma unroll
      for (int H = 0; H < 2; ++H)
        pa[g][H] = *(const bf16x8*)&Pw[(g * 16 + fr) * PSTR + H * 32 + fg * 8];
    __builtin_amdgcn_s_setprio(1);
#pragma unroll
    for (int mb = 0; mb < 4; ++mb) {
      bf16x8 vb0 = *(const bf16x8*)&Vs[(mb * 16 + fr) * 72 + fg * 8];
      bf16x8 vb1 = *(const bf16x8*)&Vs[(mb * 16 + fr) * 72 + 32 + fg * 8];
#pragma unroll
      for (int g = 0; g < 2; ++g) {
        ot[g][mb] = MFMA16(vb0, pa[g][0], ot[g][mb]);
        ot[g][mb] = MFMA16(vb1, pa[g][1], ot[g][mb]);
      }
    }
    __builtin_amdgcn_s_setprio(0);
  }

  const int b = bh >> 4, h = bh & 15;
#pragma unroll
  for (int g = 0; g < 2; ++g) {
    float l = li[g];
    l += __shfl_xor(l, 16);
    l += __shfl_xor(l, 32);
    const float inv = 1.0f / l;
    const int t = qw + g * 16 + fr;
    u16* yrow = Y + ((size_t)b * 2048 + t) * 1024 + h * 64;
#pragma unroll
    for (int mb = 0; mb < 4; ++mb) {
      const unsigned d0 = (unsigned)f2bf(ot[g][mb][0] * inv) |
                          ((unsigned)f2bf(ot[g][mb][1] * inv) << 16);
      const unsigned d1 = (unsigned)f2bf(ot[g][mb][2] * inv) |
                          ((unsigned)f2bf(ot[g][mb][3] * inv) << 16);
      *(uint2*)&yrow[mb * 16 + fg * 4] = make_uint2(d0, d1);
    }
  }
}

extern "C" void kernel_launch(void* const* d_in, const int* in_sizes, int n_in,
                              void* d_out, int out_size, void* d_ws, size_t ws_size,
                              hipStream_t stream) {
  const float* x = (const float*)d_in[0];
  const float* Wa = (const float*)d_in[1];
  const float* ba = (const float*)d_in[2];
  const float* Wp = (const float*)d_in[3];
  const float* bp = (const float*)d_in[4];
  float* out = (float*)d_out;

  char* p = (char*)d_ws;
  u16* xb = (u16*)p;   p += (size_t)8192 * 1024 * 2;
  u16* WaT = (u16*)p;  p += (size_t)3072 * 1024 * 2;
  u16* WpT = (u16*)p;  p += (size_t)1024 * 1024 * 2;
  u16* Qb = (u16*)p;   p += (size_t)64 * 2048 * 64 * 2;
  u16* Kbuf = (u16*)p; p += (size_t)64 * 2048 * 64 * 2;
  u16* Vtb = (u16*)p;  p += (size_t)64 * 64 * 2048 * 2;
  u16* Yb = (u16*)p;   p += (size_t)8192 * 1024 * 2;

  convert_bf16_k<<<4096, 256, 0, stream>>>(x, xb, 8192 * 1024);
  transpose2_k<<<1024, 256, 0, stream>>>(Wa, WaT, Wp, WpT);
  gemm_qkv_r4<<<384, 512, 0, stream>>>(xb, WaT, ba, Qb, Kbuf, Vtb);
  attn_k<<<1024, 256, 0, stream>>>(Qb, Kbuf, Vtb, Yb);
  gemm_proj_r4<<<256, 512, 0, stream>>>(Yb, WpT, bp, out);
}

// Round 9
// 240.580 us; speedup vs baseline: 1.1570x; 1.0417x over previous
//
#include <hip/hip_runtime.h>
#include <hip/hip_bf16.h>

typedef unsigned short u16;
typedef __attribute__((ext_vector_type(8))) short bf16x8;
typedef __attribute__((ext_vector_type(4))) float f32x4;

#define MFMA16(a, b, c) __builtin_amdgcn_mfma_f32_16x16x32_bf16((a), (b), (c), 0, 0, 0)

__device__ __forceinline__ u16 f2bf(float f) {
  union { float f; unsigned u; } v; v.f = f;
  unsigned r = v.u + 0x7fffu + ((v.u >> 16) & 1u);  // RNE
  return (u16)(r >> 16);
}

// pack two fp32 -> dword of 2 bf16 by truncation (1 VALU op)
__device__ __forceinline__ unsigned pk_trunc(float hi, float lo) {
  union { float f; unsigned u; } a, b; a.f = hi; b.f = lo;
  return __builtin_amdgcn_perm(a.u, b.u, 0x07060302u);
}

__device__ __forceinline__ void gload_lds16(const u16* g, u16* l) {
  __builtin_amdgcn_global_load_lds((const __attribute__((address_space(1))) void*)g,
                                   (__attribute__((address_space(3))) void*)l, 16, 0, 0);
}

// ---------------- fp32 -> bf16 convert: 8 elems/thread ----------------
__global__ __launch_bounds__(256) void convert_bf16_k(const float* __restrict__ in,
                                                      u16* __restrict__ out, int n) {
  int i = (blockIdx.x * 256 + threadIdx.x) * 8;
  if (i >= n) return;
  float4 v0 = *(const float4*)(in + i);
  float4 v1 = *(const float4*)(in + i + 4);
  uint4 o;
  o.x = (unsigned)f2bf(v0.x) | ((unsigned)f2bf(v0.y) << 16);
  o.y = (unsigned)f2bf(v0.z) | ((unsigned)f2bf(v0.w) << 16);
  o.z = (unsigned)f2bf(v1.x) | ((unsigned)f2bf(v1.y) << 16);
  o.w = (unsigned)f2bf(v1.z) | ((unsigned)f2bf(v1.w) << 16);
  *(uint4*)(out + i) = o;
}

// ---------------- fused transposes: Wa [1024][3072] and Wp [1024][1024] -> bf16 [N][K] ----------------
__global__ __launch_bounds__(256) void transpose2_k(const float* __restrict__ Wa, u16* __restrict__ WaT,
                                                    const float* __restrict__ Wp, u16* __restrict__ WpT) {
  __shared__ float tile[64][65];
  int b = blockIdx.x;
  const float* W; u16* Wt; int N, n0, k0;
  if (b < 768) { W = Wa; Wt = WaT; N = 3072; n0 = (b % 48) * 64; k0 = (b / 48) * 64; }
  else { int c = b - 768; W = Wp; Wt = WpT; N = 1024; n0 = (c & 15) * 64; k0 = (c >> 4) * 64; }
  const int tx = threadIdx.x & 63, ty = threadIdx.x >> 6;
#pragma unroll
  for (int i = 0; i < 16; ++i)
    tile[ty + 4 * i][tx] = W[(size_t)(k0 + ty + 4 * i) * N + n0 + tx];
  __syncthreads();
#pragma unroll
  for (int i = 0; i < 16; ++i)
    Wt[(size_t)(n0 + ty + 4 * i) * 1024 + k0 + tx] = f2bf(tile[tx][ty + 4 * i]);
}

// ---------------- ring-4 GEMM core: BK=32, 512 thr (8 waves 2M x 4N), ONE barrier/tile ----------------
#define BAR() asm volatile("s_barrier" ::: "memory")
#define WLG()                                                   \
  do {                                                          \
    asm volatile("s_waitcnt lgkmcnt(0)" ::: "memory");          \
    __builtin_amdgcn_sched_barrier(0);                          \
  } while (0)
#define VMW(N) asm volatile("s_waitcnt vmcnt(" #N ")" ::: "memory")

#define RING_LANE_CONSTS                                                    \
  const int tid = threadIdx.x, w = tid >> 6, lane = tid & 63;               \
  const int wm = w >> 2, wn = w & 3;                                        \
  const int fr = lane & 15, fg = lane >> 4;                                 \
  const int sr = lane >> 2;                                                 \
  const int sk = (lane & 1) * 8 + ((((lane >> 1) ^ (lane >> 5)) & 1) << 4); \
  const int lsw = fr * 32 + ((fg * 8) ^ ((fr & 8) ? 16 : 0));

// ---------------- QKV GEMM: 256x256 tile, ring-4, K=1024; LDS-transpose epilogue for Q/K ----------------
__global__ __launch_bounds__(512, 2) void gemm_qkv_r4(const u16* __restrict__ A,
                                                      const u16* __restrict__ Bt,
                                                      const float* __restrict__ bias,
                                                      u16* __restrict__ Qo, u16* __restrict__ Ko,
                                                      u16* __restrict__ Vt) {
  __shared__ u16 sm[4][16384];
  const int bid = blockIdx.x;
  const int swz = (bid & 7) * 48 + (bid >> 3);  // 384 % 8 == 0 -> bijective
  const int m0 = (swz / 12) * 256, n0 = (swz % 12) * 256;
  RING_LANE_CONSTS
  const int aoff = wm * 4096 + lsw;
  const int boff = 8192 + wn * 2048 + lsw;

  const u16* gAw = A + (size_t)(m0 + sr) * 1024 + sk + (size_t)w * 16384;
  const u16* gBw = Bt + (size_t)(n0 + sr) * 1024 + sk + (size_t)w * 16384;

#define QSTG_A(SL, C, KO) \
  gload_lds16(gAw + (size_t)(C) * 131072 + (KO), &sm[SL][(C) * 4096 + w * 512 + lane * 8])
#define QSTG_B(SL, C, KO) \
  gload_lds16(gBw + (size_t)(C) * 131072 + (KO), &sm[SL][8192 + (C) * 4096 + w * 512 + lane * 8])

  f32x4 acc[8][4];
#pragma unroll
  for (int i = 0; i < 8; ++i)
#pragma unroll
    for (int j = 0; j < 4; ++j) acc[i][j] = (f32x4){0, 0, 0, 0};

  // prologue: stage tiles 0,1,2 into slots 0,1,2; retire tile 0 (vmcnt(8))
  QSTG_A(0, 0, 0);  QSTG_B(0, 0, 0);  QSTG_A(0, 1, 0);  QSTG_B(0, 1, 0);
  QSTG_A(1, 0, 32); QSTG_B(1, 0, 32); QSTG_A(1, 1, 32); QSTG_B(1, 1, 32);
  QSTG_A(2, 0, 64); QSTG_B(2, 0, 64); QSTG_A(2, 1, 64); QSTG_B(2, 1, 64);
  int kofs = 96;
  VMW(8); BAR();

#define QLD_A(SL, M0_)                                                    \
  _Pragma("unroll") for (int i = 0; i < 4; ++i)                           \
      av[i] = *(const bf16x8*)&sm[SL][aoff + ((M0_) + i) * 512];
#define QLD_B(SL)                                                         \
  _Pragma("unroll") for (int i = 0; i < 4; ++i)                           \
      bv[i] = *(const bf16x8*)&sm[SL][boff + i * 512];
#define QMM(MB0)                                                          \
  __builtin_amdgcn_s_setprio(1);                                          \
  _Pragma("unroll") for (int i = 0; i < 4; ++i)                           \
      _Pragma("unroll") for (int j = 0; j < 4; ++j)                       \
          acc[(MB0) + i][j] = MFMA16(av[i], bv[j], acc[(MB0) + i][j]);    \
  __builtin_amdgcn_s_setprio(0);

#define QTILE(SL, SS, STG, CHK)                                                \
  {                                                                            \
    bf16x8 av[4], bv[4];                                                       \
    if (STG) { QSTG_A(SS, 0, kofs); QSTG_B(SS, 0, kofs);                       \
               QSTG_A(SS, 1, kofs); QSTG_B(SS, 1, kofs); }                     \
    QLD_A(SL, 0) QLD_B(SL)                                                     \
    WLG(); QMM(0)                                                              \
    QLD_A(SL, 4)                                                               \
    WLG(); QMM(4)                                                              \
    CHK;                                                                       \
    BAR();                                                                     \
    kofs += 32;                                                                \
  }

#pragma unroll 1
  for (int tp = 0; tp < 7; ++tp) {
    QTILE(0, 3, 1, VMW(8)) QTILE(1, 0, 1, VMW(8)) QTILE(2, 1, 1, VMW(8)) QTILE(3, 2, 1, VMW(8))
  }
  QTILE(0, 3, 1, VMW(8))   // t=28 (stages tile 31)
  QTILE(1, 0, 0, VMW(4))   // t=29
  QTILE(2, 0, 0, VMW(0))   // t=30
  QTILE(3, 0, 0, (void)0)  // t=31

  const int which = n0 >> 10;  // block-uniform: 0=Q, 1=K, 2=V (256-tile never straddles)
  if (which == 2) {
    // V: direct transposed stores (ushort4 clusters -> 32B runs), unchanged path
#pragma unroll
    for (int nb = 0; nb < 4; ++nb) {
      const int n = n0 + wn * 64 + nb * 16 + fr;
      const float bs = bias[n];
      const int c = n & 1023, h = c >> 6, hd = c & 63;
#pragma unroll
      for (int mb = 0; mb < 8; ++mb) {
        const int mbase = m0 + wm * 128 + mb * 16 + fg * 4;
        const int bb = mbase >> 11;
        const int tt = mbase & 2047;
        ushort4 pv;
        pv.x = f2bf(acc[mb][nb][0] + bs);
        pv.y = f2bf(acc[mb][nb][1] + bs);
        pv.z = f2bf(acc[mb][nb][2] + bs);
        pv.w = f2bf(acc[mb][nb][3] + bs);
        *(ushort4*)(Vt + ((size_t)(bb * 16 + h) * 64 + hd) * 2048 + tt) = pv;
      }
    }
  } else {
    // Q/K: LDS-transpose epilogue. Two passes (mb 0-3, 4-7); buf = [128 rows][256 cols] u16
    // with col-XOR swizzle (col ^ ((rl&7)<<3)) so the b128 read-back is conflict-free.
    u16* buf = &sm[0][0];
    const float sc = (which == 0) ? 0.125f : 1.0f;
    u16* outp = (which == 0) ? Qo : Ko;
    float bs4[4];
#pragma unroll
    for (int nb = 0; nb < 4; ++nb) bs4[nb] = bias[n0 + wn * 64 + nb * 16 + fr];
#pragma unroll
    for (int p = 0; p < 2; ++p) {
      // write side: rl = wm*64 + mb4*16 + fg*4 + r, col = wn*64 + nb*16 + fr
#pragma unroll
      for (int mb4 = 0; mb4 < 4; ++mb4) {
#pragma unroll
        for (int nb = 0; nb < 4; ++nb) {
#pragma unroll
          for (int r = 0; r < 4; ++r) {
            const int rl = wm * 64 + mb4 * 16 + fg * 4 + r;
            const int col = (wn * 64 + nb * 16 + fr) ^ ((rl & 7) << 3);
            buf[rl * 256 + col] = f2bf((acc[p * 4 + mb4][nb][r] + bs4[nb]) * sc);
          }
        }
      }
      BAR();
      // read side: thread owns quarter-row: rl = tid>>2, c4 = (tid&3)*64
      {
        const int rl = tid >> 2, c4 = (tid & 3) * 64;
        const int m = m0 + (rl >> 6) * 128 + p * 64 + (rl & 63);
        const int bb = m >> 11, tt = m & 2047;
        const int n = n0 + c4;
        const int h = (n & 1023) >> 6;
        u16* dst = outp + ((size_t)(bb * 16 + h) * 2048 + tt) * 64;  // hd 0..63 contiguous
#pragma unroll
        for (int i = 0; i < 8; ++i) {
          const int col = (c4 + i * 8) ^ ((rl & 7) << 3);
          *(uint4*)(dst + i * 8) = *(const uint4*)&buf[rl * 256 + col];
        }
      }
      BAR();
    }
  }
#undef QSTG_A
#undef QSTG_B
#undef QLD_A
#undef QLD_B
#undef QMM
#undef QTILE
}

// ---------------- Proj GEMM: 256x128 tile, ring-4, ONE barrier/tile; grid = 256 ----------------
__global__ __launch_bounds__(512, 2) void gemm_proj_r4(const u16* __restrict__ A,
                                                       const u16* __restrict__ Bt,
                                                       const float* __restrict__ bias,
                                                       float* __restrict__ O) {
  __shared__ u16 sm[4][12288];
  const int bid = blockIdx.x;
  const int swz = (bid & 7) * 32 + (bid >> 3);  // 256 % 8 == 0 -> bijective
  const int m0 = (swz >> 3) * 256, n0 = (swz & 7) * 128;
  RING_LANE_CONSTS
  const int aoff = wm * 4096 + lsw;
  const int boff = 8192 + wn * 1024 + lsw;

  const u16* gAw = A + (size_t)(m0 + sr) * 1024 + sk + (size_t)w * 16384;
  const u16* gBw = Bt + (size_t)(n0 + sr) * 1024 + sk + (size_t)w * 16384;

#define PSTG_A(SL, C, KO) \
  gload_lds16(gAw + (size_t)(C) * 131072 + (KO), &sm[SL][(C) * 4096 + w * 512 + lane * 8])
#define PSTG_B(SL, KO) \
  gload_lds16(gBw + (KO), &sm[SL][8192 + w * 512 + lane * 8])

  f32x4 acc[8][2];
#pragma unroll
  for (int i = 0; i < 8; ++i)
#pragma unroll
    for (int j = 0; j < 2; ++j) acc[i][j] = (f32x4){0, 0, 0, 0};

  PSTG_A(0, 0, 0);  PSTG_B(0, 0);  PSTG_A(0, 1, 0);
  PSTG_A(1, 0, 32); PSTG_B(1, 32); PSTG_A(1, 1, 32);
  PSTG_A(2, 0, 64); PSTG_B(2, 64); PSTG_A(2, 1, 64);
  int kofs = 96;
  VMW(6); BAR();

#define PLD_A(SL, M0_)                                                    \
  _Pragma("unroll") for (int i = 0; i < 4; ++i)                           \
      av[i] = *(const bf16x8*)&sm[SL][aoff + ((M0_) + i) * 512];
#define PLD_B(SL)                                                         \
  _Pragma("unroll") for (int i = 0; i < 2; ++i)                           \
      bv[i] = *(const bf16x8*)&sm[SL][boff + i * 512];
#define PMM(MB0)                                                          \
  __builtin_amdgcn_s_setprio(1);                                          \
  _Pragma("unroll") for (int i = 0; i < 4; ++i)                           \
      _Pragma("unroll") for (int j = 0; j < 2; ++j)                       \
          acc[(MB0) + i][j] = MFMA16(av[i], bv[j], acc[(MB0) + i][j]);    \
  __builtin_amdgcn_s_setprio(0);

#define PTILE(SL, SS, STG, CHK)                                                \
  {                                                                            \
    bf16x8 av[4], bv[2];                                                       \
    if (STG) { PSTG_A(SS, 0, kofs); PSTG_B(SS, kofs); PSTG_A(SS, 1, kofs); }   \
    PLD_A(SL, 0) PLD_B(SL)                                                     \
    WLG(); PMM(0)                                                              \
    PLD_A(SL, 4)                                                               \
    WLG(); PMM(4)                                                              \
    CHK;                                                                       \
    BAR();                                                                     \
    kofs += 32;                                                                \
  }

#pragma unroll 1
  for (int tp = 0; tp < 7; ++tp) {
    PTILE(0, 3, 1, VMW(6)) PTILE(1, 0, 1, VMW(6)) PTILE(2, 1, 1, VMW(6)) PTILE(3, 2, 1, VMW(6))
  }
  PTILE(0, 3, 1, VMW(6))
  PTILE(1, 0, 0, VMW(3))
  PTILE(2, 0, 0, VMW(0))
  PTILE(3, 0, 0, (void)0)

#pragma unroll
  for (int nb = 0; nb < 2; ++nb) {
    const int n = n0 + wn * 32 + nb * 16 + fr;
    const float bs = bias[n];
#pragma unroll
    for (int mb = 0; mb < 8; ++mb) {
      const int tg = m0 + wm * 128 + mb * 16 + fg * 4;
#pragma unroll
      for (int r = 0; r < 4; ++r) O[(size_t)(tg + r) * 1024 + n] = acc[mb][nb][r] + bs;
    }
  }
#undef PSTG_A
#undef PSTG_B
#undef PLD_A
#undef PLD_B
#undef PMM
#undef PTILE
}

// ---------------- Flash attention: 128 q/block (32/wave), balanced qt map + T5 setprio ----------------
#define PSTR 72
__global__ __launch_bounds__(256) void attn_k(const u16* __restrict__ Q,
                                              const u16* __restrict__ Kb,
                                              const u16* __restrict__ Vt,
                                              u16* __restrict__ Y) {
  __shared__ u16 Ks[64 * 72];
  __shared__ u16 Vs[64 * 72];
  __shared__ u16 Ps[4 * 32 * PSTR];
  const int L = blockIdx.x;
  const int xcd = L & 7, slot = L >> 3;
  const int bh = xcd * 8 + (slot & 7);
  const int i2 = slot >> 3;
  const int qt = (i2 & 4) ? ((i2 & 8) ? 4 + (i2 & 3) : (i2 & 3))
                          : ((i2 & 8) ? 11 - (i2 & 3) : 15 - (i2 & 3));
  const int tid = threadIdx.x, w = tid >> 6, lane = tid & 63;
  const int fr = lane & 15, fg = lane >> 4;
  const u16* Qp = Q + (size_t)bh * 2048 * 64;
  const u16* Kp = Kb + (size_t)bh * 2048 * 64;
  const u16* Vp = Vt + (size_t)bh * 64 * 2048;
  const int qw = qt * 128 + w * 32;

  bf16x8 qa[2][2];
#pragma unroll
  for (int g = 0; g < 2; ++g)
#pragma unroll
    for (int c = 0; c < 2; ++c)
      qa[g][c] = *(const bf16x8*)(Qp + (size_t)(qw + g * 16 + fr) * 64 + c * 32 + fg * 8);

  float li[2] = {0.f, 0.f};
  f32x4 ot[2][4];
#pragma unroll
  for (int g = 0; g < 2; ++g)
#pragma unroll
    for (int mb = 0; mb < 4; ++mb) ot[g][mb] = (f32x4){0, 0, 0, 0};

  const int srow = tid >> 2, scol = (tid & 3) * 16;
  u16* Pw = Ps + w * 32 * PSTR;
  const int nk = 2 * qt + 2;
  const u16* Kg = Kp + (size_t)srow * 64 + scol;
  const u16* Vg = Vp + (size_t)srow * 2048 + scol;

  uint4 kr0 = *(const uint4*)(Kg);
  uint4 kr1 = *(const uint4*)(Kg + 8);
  uint4 vr0 = *(const uint4*)(Vg);
  uint4 vr1 = *(const uint4*)(Vg + 8);

  for (int jt = 0; jt < nk; ++jt) {
    const int k0 = jt * 64;
    if (jt) __syncthreads();
    *(uint4*)&Ks[srow * 72 + scol] = kr0;
    *(uint4*)&Ks[srow * 72 + scol + 8] = kr1;
    *(uint4*)&Vs[srow * 72 + scol] = vr0;
    *(uint4*)&Vs[srow * 72 + scol + 8] = vr1;
    __syncthreads();
    if (jt + 1 < nk) {
      const int kn = (jt + 1) * 64;
      kr0 = *(const uint4*)(Kg + (size_t)kn * 64);
      kr1 = *(const uint4*)(Kg + (size_t)kn * 64 + 8);
      vr0 = *(const uint4*)(Vg + kn);
      vr1 = *(const uint4*)(Vg + kn + 8);
    }
    if (k0 > qw + 31) continue;

    bf16x8 kb[4][2];
#pragma unroll
    for (int nb = 0; nb < 4; ++nb) {
      kb[nb][0] = *(const bf16x8*)&Ks[(nb * 16 + fr) * 72 + fg * 8];
      kb[nb][1] = *(const bf16x8*)&Ks[(nb * 16 + fr) * 72 + 32 + fg * 8];
    }
    f32x4 st[2][4];
    __builtin_amdgcn_s_setprio(1);
#pragma unroll
    for (int g = 0; g < 2; ++g)
#pragma unroll
      for (int nb = 0; nb < 4; ++nb) {
        f32x4 z = (f32x4){0, 0, 0, 0};
        z = MFMA16(kb[nb][0], qa[g][0], z);
        z = MFMA16(kb[nb][1], qa[g][1], z);
        st[g][nb] = z;
      }
    __builtin_amdgcn_s_setprio(0);
    const bool needmask = (k0 + 63 > qw);
#pragma unroll
    for (int g = 0; g < 2; ++g) {
      const int q = qw + g * 16 + fr;
      float rs0 = 0.f, rs1 = 0.f;
#pragma unroll
      for (int nb = 0; nb < 4; ++nb) {
        const int kcb = k0 + nb * 16 + 4 * fg;
        float p0 = __expf(st[g][nb][0]);
        float p1 = __expf(st[g][nb][1]);
        float p2 = __expf(st[g][nb][2]);
        float p3 = __expf(st[g][nb][3]);
        if (needmask) {
          p0 = (kcb + 0 > q) ? 0.f : p0;
          p1 = (kcb + 1 > q) ? 0.f : p1;
          p2 = (kcb + 2 > q) ? 0.f : p2;
          p3 = (kcb + 3 > q) ? 0.f : p3;
        }
        rs0 += p0 + p1;
        rs1 += p2 + p3;
        *(uint2*)&Pw[(g * 16 + fr) * PSTR + nb * 16 + 4 * fg] =
            make_uint2(pk_trunc(p1, p0), pk_trunc(p3, p2));
      }
      li[g] += rs0 + rs1;
    }
    bf16x8 pa[2][2];
#pragma unroll
    for (int g = 0; g < 2; ++g)
#pragma unroll
      for (int H = 0; H < 2; ++H)
        pa[g][H] = *(const bf16x8*)&Pw[(g * 16 + fr) * PSTR + H * 32 + fg * 8];
    __builtin_amdgcn_s_setprio(1);
#pragma unroll
    for (int mb = 0; mb < 4; ++mb) {
      bf16x8 vb0 = *(const bf16x8*)&Vs[(mb * 16 + fr) * 72 + fg * 8];
      bf16x8 vb1 = *(const bf16x8*)&Vs[(mb * 16 + fr) * 72 + 32 + fg * 8];
#pragma unroll
      for (int g = 0; g < 2; ++g) {
        ot[g][mb] = MFMA16(vb0, pa[g][0], ot[g][mb]);
        ot[g][mb] = MFMA16(vb1, pa[g][1], ot[g][mb]);
      }
    }
    __builtin_amdgcn_s_setprio(0);
  }

  const int b = bh >> 4, h = bh & 15;
#pragma unroll
  for (int g = 0; g < 2; ++g) {
    float l = li[g];
    l += __shfl_xor(l, 16);
    l += __shfl_xor(l, 32);
    const float inv = 1.0f / l;
    const int t = qw + g * 16 + fr;
    u16* yrow = Y + ((size_t)b * 2048 + t) * 1024 + h * 64;
#pragma unroll
    for (int mb = 0; mb < 4; ++mb) {
      const unsigned d0 = (unsigned)f2bf(ot[g][mb][0] * inv) |
                          ((unsigned)f2bf(ot[g][mb][1] * inv) << 16);
      const unsigned d1 = (unsigned)f2bf(ot[g][mb][2] * inv) |
                          ((unsigned)f2bf(ot[g][mb][3] * inv) << 16);
      *(uint2*)&yrow[mb * 16 + fg * 4] = make_uint2(d0, d1);
    }
  }
}

extern "C" void kernel_launch(void* const* d_in, const int* in_sizes, int n_in,
                              void* d_out, int out_size, void* d_ws, size_t ws_size,
                              hipStream_t stream) {
  const float* x = (const float*)d_in[0];
  const float* Wa = (const float*)d_in[1];
  const float* ba = (const float*)d_in[2];
  const float* Wp = (const float*)d_in[3];
  const float* bp = (const float*)d_in[4];
  float* out = (float*)d_out;

  char* p = (char*)d_ws;
  u16* xb = (u16*)p;   p += (size_t)8192 * 1024 * 2;
  u16* WaT = (u16*)p;  p += (size_t)3072 * 1024 * 2;
  u16* WpT = (u16*)p;  p += (size_t)1024 * 1024 * 2;
  u16* Qb = (u16*)p;   p += (size_t)64 * 2048 * 64 * 2;
  u16* Kbuf = (u16*)p; p += (size_t)64 * 2048 * 64 * 2;
  u16* Vtb = (u16*)p;  p += (size_t)64 * 64 * 2048 * 2;
  u16* Yb = (u16*)p;   p += (size_t)8192 * 1024 * 2;

  convert_bf16_k<<<4096, 256, 0, stream>>>(x, xb, 8192 * 1024);
  transpose2_k<<<1024, 256, 0, stream>>>(Wa, WaT, Wp, WpT);
  gemm_qkv_r4<<<384, 512, 0, stream>>>(xb, WaT, ba, Qb, Kbuf, Vtb);
  attn_k<<<1024, 256, 0, stream>>>(Qb, Kbuf, Vtb, Yb);
  gemm_proj_r4<<<256, 512, 0, stream>>>(Yb, WpT, bp, out);
}